// Round 1
// baseline (353.567 us; speedup 1.0000x reference)
//
#include <hip/hip_runtime.h>
#include <hip/hip_bf16.h>
#include <stdint.h>

// ---------------------------------------------------------------------------
// LazyGGUFLinear: y = x @ dequant(scales, codes)^T
//   x:      [2,2048,4096] fp32  -> M=4096, K=4096
//   scales: [4096,128]    fp32
//   codes:  [4096,128,32] int32 (0..255; signed = code-128)
//   y:      [2,2048,4096] fp32  -> [M=4096, N=4096]
// Strategy: dequant W -> bf16 (ws), convert x -> bf16 (ws), then the
// m97-verified 128x128 / BK=32 MFMA GEMM (16x16x32 bf16) at ~900 TF.
// ---------------------------------------------------------------------------

#define M_DIM 4096
#define N_DIM 4096
#define K_DIM 4096
#define TILE 128
#define BK 32

typedef __attribute__((ext_vector_type(8))) short bf16x8;   // 8 bf16 = 4 VGPRs
typedef __attribute__((ext_vector_type(4))) float f32x4;    // MFMA C/D

__device__ __forceinline__ unsigned short f32_to_bf16_rne(float f) {
    unsigned u = __float_as_uint(f);
    u += 0x7fffu + ((u >> 16) & 1u);   // round-to-nearest-even
    return (unsigned short)(u >> 16);
}

__device__ __forceinline__ void load_lds16(const void* g, void* l) {
    // async global->LDS, 16 B per lane; LDS dest = wave-uniform base + lane*16
    __builtin_amdgcn_global_load_lds(
        (const __attribute__((address_space(1))) unsigned int*)g,
        (__attribute__((address_space(3))) unsigned int*)l, 16, 0, 0);
}

// ---- kernel 1: dequantize codes -> bf16 weight [N, K] row-major ------------
// one thread per 8 consecutive weights (stays inside one 32-block)
__global__ __launch_bounds__(256) void dequant_w_kernel(
        const int* __restrict__ codes, const float* __restrict__ scales,
        unsigned short* __restrict__ W) {
    const int tid = blockIdx.x * 256 + threadIdx.x;       // 2,097,152 threads
    const int o   = tid >> 9;                             // row (out)
    const int blk = (tid & 511) >> 2;                     // 32-block index
    const float s = scales[o * 128 + blk];
    const int4 c0 = ((const int4*)codes)[(size_t)tid * 2];
    const int4 c1 = ((const int4*)codes)[(size_t)tid * 2 + 1];
    union { unsigned short u[8]; uint4 v; } p;
    p.u[0] = f32_to_bf16_rne(s * (float)(c0.x - 128));
    p.u[1] = f32_to_bf16_rne(s * (float)(c0.y - 128));
    p.u[2] = f32_to_bf16_rne(s * (float)(c0.z - 128));
    p.u[3] = f32_to_bf16_rne(s * (float)(c0.w - 128));
    p.u[4] = f32_to_bf16_rne(s * (float)(c1.x - 128));
    p.u[5] = f32_to_bf16_rne(s * (float)(c1.y - 128));
    p.u[6] = f32_to_bf16_rne(s * (float)(c1.z - 128));
    p.u[7] = f32_to_bf16_rne(s * (float)(c1.w - 128));
    ((uint4*)W)[tid] = p.v;
}

// ---- kernel 2: x fp32 -> bf16 ----------------------------------------------
__global__ __launch_bounds__(256) void cvt_x_kernel(
        const float* __restrict__ x, unsigned short* __restrict__ xb) {
    const int tid = blockIdx.x * 256 + threadIdx.x;       // one per 8 floats
    const float4 f0 = ((const float4*)x)[(size_t)tid * 2];
    const float4 f1 = ((const float4*)x)[(size_t)tid * 2 + 1];
    union { unsigned short u[8]; uint4 v; } p;
    p.u[0] = f32_to_bf16_rne(f0.x); p.u[1] = f32_to_bf16_rne(f0.y);
    p.u[2] = f32_to_bf16_rne(f0.z); p.u[3] = f32_to_bf16_rne(f0.w);
    p.u[4] = f32_to_bf16_rne(f1.x); p.u[5] = f32_to_bf16_rne(f1.y);
    p.u[6] = f32_to_bf16_rne(f1.z); p.u[7] = f32_to_bf16_rne(f1.w);
    ((uint4*)xb)[tid] = p.v;
}

// ---- kernel 3: bf16 GEMM, B^T layout (both A and B are K-major) ------------
// C[m,n] = sum_k A[m,k] * B[n,k].  128x128 tile, BK=32, 4 waves, 64x64/wave,
// 4x4 grid of 16x16x32 MFMAs per wave per K-step. m97 structure (~900 TF).
__global__ __launch_bounds__(256) void gemm_bt_kernel(
        const unsigned short* __restrict__ A,   // [M,K] bf16
        const unsigned short* __restrict__ B,   // [N,K] bf16
        float* __restrict__ C) {                // [M,N] fp32
    __shared__ unsigned short As[TILE * BK];    // 8 KB
    __shared__ unsigned short Bs[TILE * BK];    // 8 KB

    const int wave = threadIdx.x >> 6;
    const int lane = threadIdx.x & 63;
    const int m0 = blockIdx.y * TILE;
    const int n0 = blockIdx.x * TILE;

    // staging addressing: each wave-inst covers 16 rows x 32 k (1 KB)
    const int srow  = lane >> 2;            // 0..15 within 16-row group
    const int skofs = (lane & 3) * 8;       // k element offset: 0,8,16,24
    const int wrow0 = wave * 32;            // this wave stages rows [wrow0, wrow0+32)

    const unsigned short* Ag = A + (size_t)(m0 + wrow0 + srow) * K_DIM + skofs;
    const unsigned short* Bg = B + (size_t)(n0 + wrow0 + srow) * K_DIM + skofs;
    unsigned short* AsBase = &As[wrow0 * BK];   // wave-uniform LDS bases
    unsigned short* BsBase = &Bs[wrow0 * BK];

    // fragment addressing (A-operand layout: row = lane&15, k = quad*8 + j)
    const int frow = lane & 15;
    const int quad = lane >> 4;
    const int wm = (wave >> 1) * 64;        // wave's 64x64 subtile
    const int wn = (wave & 1) * 64;

    f32x4 acc[4][4] = {};

    for (int k0 = 0; k0 < K_DIM; k0 += BK) {
        load_lds16(Ag + k0,               AsBase);
        load_lds16(Ag + k0 + 16 * K_DIM,  AsBase + 16 * BK);
        load_lds16(Bg + k0,               BsBase);
        load_lds16(Bg + k0 + 16 * K_DIM,  BsBase + 16 * BK);
        __syncthreads();    // drains vmcnt (global_load_lds) + barrier

        bf16x8 a[4], b[4];
#pragma unroll
        for (int t = 0; t < 4; ++t) {
            a[t] = *(const bf16x8*)&As[(wm + t * 16 + frow) * BK + quad * 8];
            b[t] = *(const bf16x8*)&Bs[(wn + t * 16 + frow) * BK + quad * 8];
        }
#pragma unroll
        for (int mt = 0; mt < 4; ++mt)
#pragma unroll
            for (int nt = 0; nt < 4; ++nt)
                acc[mt][nt] = __builtin_amdgcn_mfma_f32_16x16x32_bf16(
                    a[mt], b[nt], acc[mt][nt], 0, 0, 0);
        __syncthreads();    // protect LDS before next staging overwrite
    }

    // epilogue: C/D layout col = lane&15, row = quad*4 + reg  [m89/m91 verified]
#pragma unroll
    for (int mt = 0; mt < 4; ++mt)
#pragma unroll
        for (int nt = 0; nt < 4; ++nt)
#pragma unroll
            for (int r = 0; r < 4; ++r) {
                const int row = m0 + wm + mt * 16 + quad * 4 + r;
                const int col = n0 + wn + nt * 16 + frow;
                C[(size_t)row * N_DIM + col] = acc[mt][nt][r];
            }
}

extern "C" void kernel_launch(void* const* d_in, const int* in_sizes, int n_in,
                              void* d_out, int out_size, void* d_ws, size_t ws_size,
                              hipStream_t stream) {
    const float* x      = (const float*)d_in[0];   // 2*2048*4096 fp32
    const float* scales = (const float*)d_in[1];   // 4096*128 fp32
    const int*   codes  = (const int*)d_in[2];     // 4096*128*32 int32
    float* y = (float*)d_out;                      // 4096*4096 fp32

    unsigned short* Wb = (unsigned short*)d_ws;                       // 32 MB
    unsigned short* xb = (unsigned short*)((char*)d_ws + (size_t)N_DIM * K_DIM * 2); // 32 MB

    // 16.7M elements / 8 per thread / 256 per block = 8192 blocks
    dequant_w_kernel<<<8192, 256, 0, stream>>>(codes, scales, Wb);
    cvt_x_kernel<<<8192, 256, 0, stream>>>(x, xb);

    dim3 grid(N_DIM / TILE, M_DIM / TILE);  // 32 x 32
    gemm_bt_kernel<<<grid, 256, 0, stream>>>(xb, Wb, y);
}

// Round 2
// 317.038 us; speedup vs baseline: 1.1152x; 1.1152x over previous
//
#include <hip/hip_runtime.h>
#include <hip/hip_bf16.h>
#include <stdint.h>

// ---------------------------------------------------------------------------
// LazyGGUFLinear: y = x @ dequant(scales, codes)^T   (M=N=K=4096)
// R1: 3 kernels, GEMM BK=32 -> 217us GEMM (633 TF), 353us total.
// R2: BK=64 (half the barrier drains), XOR bank-conflict swizzle on fragment
//     reads (R1: 1.68e7 conflict cycles), XCD-rectangle block swizzle for L2
//     locality (R1 FETCH 164MB vs 64 ideal), fused prologue (1 launch).
// ---------------------------------------------------------------------------

#define M_DIM 4096
#define N_DIM 4096
#define K_DIM 4096
#define TILE 128
#define BK 64

typedef __attribute__((ext_vector_type(8))) short bf16x8;   // 8 bf16 = 4 VGPRs
typedef __attribute__((ext_vector_type(4))) float f32x4;    // MFMA C/D

__device__ __forceinline__ unsigned short f32_to_bf16_rne(float f) {
    unsigned u = __float_as_uint(f);
    u += 0x7fffu + ((u >> 16) & 1u);   // round-to-nearest-even
    return (unsigned short)(u >> 16);
}

__device__ __forceinline__ void load_lds16(const void* g, void* l) {
    // async global->LDS, 16 B per lane; LDS dest = wave-uniform base + lane*16
    __builtin_amdgcn_global_load_lds(
        (const __attribute__((address_space(1))) unsigned int*)g,
        (__attribute__((address_space(3))) unsigned int*)l, 16, 0, 0);
}

// ---- fused prologue: blocks [0,8192) dequant W, [8192,16384) convert x -----
__global__ __launch_bounds__(256) void prologue_kernel(
        const int* __restrict__ codes, const float* __restrict__ scales,
        unsigned short* __restrict__ W,
        const float* __restrict__ x, unsigned short* __restrict__ xb) {
    const int bid = blockIdx.x;
    if (bid < 8192) {
        // dequant: one thread per 8 consecutive weights (inside one 32-block)
        const int tid = bid * 256 + threadIdx.x;          // 2,097,152 threads
        const int o   = tid >> 9;
        const int blk = (tid & 511) >> 2;
        const float s = scales[o * 128 + blk];
        const int4 c0 = ((const int4*)codes)[(size_t)tid * 2];
        const int4 c1 = ((const int4*)codes)[(size_t)tid * 2 + 1];
        union { unsigned short u[8]; uint4 v; } p;
        p.u[0] = f32_to_bf16_rne(s * (float)(c0.x - 128));
        p.u[1] = f32_to_bf16_rne(s * (float)(c0.y - 128));
        p.u[2] = f32_to_bf16_rne(s * (float)(c0.z - 128));
        p.u[3] = f32_to_bf16_rne(s * (float)(c0.w - 128));
        p.u[4] = f32_to_bf16_rne(s * (float)(c1.x - 128));
        p.u[5] = f32_to_bf16_rne(s * (float)(c1.y - 128));
        p.u[6] = f32_to_bf16_rne(s * (float)(c1.z - 128));
        p.u[7] = f32_to_bf16_rne(s * (float)(c1.w - 128));
        ((uint4*)W)[tid] = p.v;
    } else {
        const int tid = (bid - 8192) * 256 + threadIdx.x; // one per 8 floats
        const float4 f0 = ((const float4*)x)[(size_t)tid * 2];
        const float4 f1 = ((const float4*)x)[(size_t)tid * 2 + 1];
        union { unsigned short u[8]; uint4 v; } p;
        p.u[0] = f32_to_bf16_rne(f0.x); p.u[1] = f32_to_bf16_rne(f0.y);
        p.u[2] = f32_to_bf16_rne(f0.z); p.u[3] = f32_to_bf16_rne(f0.w);
        p.u[4] = f32_to_bf16_rne(f1.x); p.u[5] = f32_to_bf16_rne(f1.y);
        p.u[6] = f32_to_bf16_rne(f1.z); p.u[7] = f32_to_bf16_rne(f1.w);
        ((uint4*)xb)[tid] = p.v;
    }
}

// ---- bf16 GEMM, both operands K-major. 128x128 tile, BK=64, 4 waves -------
// LDS layout: row-major [row][chunk], chunk = 8 shorts; LDS chunk c of row r
// holds GLOBAL k-chunk (c ^ (r&7)) -- staging XORs the global source offset,
// keeping the global_load_lds LDS dest contiguous (lane*16). Fragment reads
// un-XOR -> 16 lanes/quad spread over all 32 banks (was 8-way conflict).
__global__ __launch_bounds__(256) void gemm_bt_kernel(
        const unsigned short* __restrict__ A,   // [M,K] bf16 (x)
        const unsigned short* __restrict__ B,   // [N,K] bf16 (W)
        float* __restrict__ C) {                // [M,N] fp32
    __shared__ unsigned short As[TILE * BK];    // 16 KB
    __shared__ unsigned short Bs[TILE * BK];    // 16 KB

    const int wave = threadIdx.x >> 6;
    const int lane = threadIdx.x & 63;

    // XCD-rectangle swizzle: xcd = b%8 [m09]; XCD x owns a 16(m) x 8(n)
    // rectangle of the 32x32 tile grid -> concurrent footprint 24MB/XCD.
    const int b   = blockIdx.x;           // 0..1023
    const int i   = b >> 3;               // 0..127 slot within XCD
    const int mt0 = ((b >> 2) & 1) * 16 + (i & 15);   // 0..31
    const int nt0 = (b & 3) * 8 + (i >> 4);           // 0..31
    const int m0 = mt0 * TILE;
    const int n0 = nt0 * TILE;

    // staging: each inst = 64 lanes x 16B = 8 rows x 64k; 4 insts per operand
    // per wave (wave stages 32 rows). Global k-offset XOR-swizzled by row&7.
    const int srow  = lane >> 3;                          // 0..7
    const int skofs = ((lane & 7) ^ srow) * 8;            // XOR swizzle
    const int wrow0 = wave * 32;

    const unsigned short* Ag = A + (size_t)(m0 + wrow0 + srow) * K_DIM + skofs;
    const unsigned short* Bg = B + (size_t)(n0 + wrow0 + srow) * K_DIM + skofs;
    unsigned short* AsBase = &As[wrow0 * BK];   // wave-uniform LDS bases
    unsigned short* BsBase = &Bs[wrow0 * BK];

    // fragment addressing (A-operand layout: row = lane&15, k = quad*8 + j)
    const int frow = lane & 15;
    const int quad = lane >> 4;
    const int wm = (wave >> 1) * 64;        // wave's 64x64 subtile
    const int wn = (wave & 1) * 64;

    f32x4 acc[4][4] = {};

    for (int k0 = 0; k0 < K_DIM; k0 += BK) {
#pragma unroll
        for (int j = 0; j < 4; ++j) {
            load_lds16(Ag + k0 + j * 8 * K_DIM, AsBase + j * 8 * BK);
            load_lds16(Bg + k0 + j * 8 * K_DIM, BsBase + j * 8 * BK);
        }
        __syncthreads();    // drains vmcnt (global_load_lds) + barrier

#pragma unroll
        for (int h = 0; h < 2; ++h) {       // two 16x16x32 K-halves of BK=64
            bf16x8 a[4], bfr[4];
#pragma unroll
            for (int t = 0; t < 4; ++t) {
                const int ar = wm + t * 16 + frow;
                const int br = wn + t * 16 + frow;
                const int ch = (h * 4 + quad) ^ (frow & 7);   // un-XOR
                a[t]   = *(const bf16x8*)&As[ar * BK + ch * 8];
                bfr[t] = *(const bf16x8*)&Bs[br * BK + ch * 8];
            }
#pragma unroll
            for (int mt = 0; mt < 4; ++mt)
#pragma unroll
                for (int nt = 0; nt < 4; ++nt)
                    acc[mt][nt] = __builtin_amdgcn_mfma_f32_16x16x32_bf16(
                        a[mt], bfr[nt], acc[mt][nt], 0, 0, 0);
        }
        __syncthreads();    // protect LDS before next staging overwrite
    }

    // epilogue: C/D layout col = lane&15, row = quad*4 + reg  [m89/m91]
#pragma unroll
    for (int mt = 0; mt < 4; ++mt)
#pragma unroll
        for (int nt = 0; nt < 4; ++nt)
#pragma unroll
            for (int r = 0; r < 4; ++r) {
                const int row = m0 + wm + mt * 16 + quad * 4 + r;
                const int col = n0 + wn + nt * 16 + frow;
                C[(size_t)row * N_DIM + col] = acc[mt][nt][r];
            }
}

extern "C" void kernel_launch(void* const* d_in, const int* in_sizes, int n_in,
                              void* d_out, int out_size, void* d_ws, size_t ws_size,
                              hipStream_t stream) {
    const float* x      = (const float*)d_in[0];   // 2*2048*4096 fp32
    const float* scales = (const float*)d_in[1];   // 4096*128 fp32
    const int*   codes  = (const int*)d_in[2];     // 4096*128*32 int32
    float* y = (float*)d_out;                      // 4096*4096 fp32

    unsigned short* Wb = (unsigned short*)d_ws;                       // 32 MB
    unsigned short* xb = (unsigned short*)((char*)d_ws + (size_t)N_DIM * K_DIM * 2); // 32 MB

    prologue_kernel<<<16384, 256, 0, stream>>>(codes, scales, Wb, x, xb);

    gemm_bt_kernel<<<1024, 256, 0, stream>>>(xb, Wb, y);
}